// Round 1
// baseline (72.421 us; speedup 1.0000x reference)
//
#include <hip/hip_runtime.h>
#include <cstddef>

#define BATCH 512
#define UNITS 512
#define HID   64

typedef __bf16 bf16x8 __attribute__((ext_vector_type(8)));
typedef float  f32x4  __attribute__((ext_vector_type(4)));

__device__ __forceinline__ float fast_sigmoid(float v) {
    return 1.0f / (1.0f + __expf(-v));
}
__device__ __forceinline__ float fast_tanh(float v) {
    return 2.0f / (1.0f + __expf(-2.0f * v)) - 1.0f;
}

// One block per unit. 4 waves = 2(M) x 2(N). Wave tile = 32 rows x 32 cols.
// Block processes 64 batch rows per iteration, 8 iterations.
// All 6 weight matrices (64x64) held in registers as MFMA B-fragments.
__global__ __launch_bounds__(256, 2)
void gru_kernel(const float* __restrict__ x,    const float* __restrict__ h,
                const float* __restrict__ W_ir, const float* __restrict__ b_ir,
                const float* __restrict__ W_hr, const float* __restrict__ b_hr,
                const float* __restrict__ W_iz, const float* __restrict__ b_iz,
                const float* __restrict__ W_hz, const float* __restrict__ b_hz,
                const float* __restrict__ W_in, const float* __restrict__ b_in,
                const float* __restrict__ W_hn, const float* __restrict__ b_hn,
                float* __restrict__ out)
{
    const int u    = blockIdx.x;
    const int tid  = threadIdx.x;
    const int lane = tid & 63;
    const int w    = tid >> 6;
    const int wm   = w >> 1;     // 0..1 : M half
    const int wn   = w & 1;      // 0..1 : N half
    const int lr   = lane & 15;  // row (A) / col (B,D) within fragment
    const int lg   = lane >> 4;  // k-group 0..3

    const float* Wp0 = W_ir + (size_t)u * 64 * 64;
    const float* Wp1 = W_hr + (size_t)u * 64 * 64;
    const float* Wp2 = W_iz + (size_t)u * 64 * 64;
    const float* Wp3 = W_hz + (size_t)u * 64 * 64;
    const float* Wp4 = W_in + (size_t)u * 64 * 64;
    const float* Wp5 = W_hn + (size_t)u * 64 * 64;
    const float* Wp[6] = { Wp0, Wp1, Wp2, Wp3, Wp4, Wp5 };

    // ---- load all weight B-fragments into registers (once per block) ----
    // B-frag for out[b][o] = sum_i A[b][i] * W[i][o]: lane holds W[i0+e][o],
    // o = wn*32 + n*16 + lr, i = ks*32 + lg*8 + e  (same k-map as A side).
    bf16x8 bw[6][2][2];
    #pragma unroll
    for (int g = 0; g < 6; ++g) {
      #pragma unroll
      for (int n = 0; n < 2; ++n) {
        const int o = wn * 32 + n * 16 + lr;
        #pragma unroll
        for (int ks = 0; ks < 2; ++ks) {
          const int i0 = ks * 32 + lg * 8;
          const float* p = Wp[g] + (size_t)i0 * 64 + o;
          bf16x8 f;
          #pragma unroll
          for (int e = 0; e < 8; ++e) f[e] = (__bf16)p[(size_t)e * 64];
          bw[g][n][ks] = f;
        }
      }
    }

    // ---- per-lane biases (col o fixed per n-fragment) ----
    float brs[2], bzs[2], bins[2], bhns[2];
    #pragma unroll
    for (int n = 0; n < 2; ++n) {
      const int o = wn * 32 + n * 16 + lr;
      brs[n]  = b_ir[u * 64 + o] + b_hr[u * 64 + o];
      bzs[n]  = b_iz[u * 64 + o] + b_hz[u * 64 + o];
      bins[n] = b_in[u * 64 + o];
      bhns[n] = b_hn[u * 64 + o];
    }

    const f32x4 zero4 = { 0.0f, 0.0f, 0.0f, 0.0f };

    for (int it = 0; it < BATCH / 64; ++it) {
      const int brow0 = it * 64 + wm * 32;

      // ---- A fragments: x,h rows -> bf16x8 (8 contiguous k per lane) ----
      bf16x8 ax[2][2], ah[2][2];
      #pragma unroll
      for (int m = 0; m < 2; ++m) {
        const int row = brow0 + m * 16 + lr;
        const float* px = x + ((size_t)row * UNITS + u) * HID;
        const float* ph = h + ((size_t)row * UNITS + u) * HID;
        #pragma unroll
        for (int ks = 0; ks < 2; ++ks) {
          const int i0 = ks * 32 + lg * 8;
          f32x4 xv0 = *(const f32x4*)(px + i0);
          f32x4 xv1 = *(const f32x4*)(px + i0 + 4);
          f32x4 hv0 = *(const f32x4*)(ph + i0);
          f32x4 hv1 = *(const f32x4*)(ph + i0 + 4);
          bf16x8 fx, fh;
          #pragma unroll
          for (int e = 0; e < 4; ++e) {
            fx[e]     = (__bf16)xv0[e];
            fx[4 + e] = (__bf16)xv1[e];
            fh[e]     = (__bf16)hv0[e];
            fh[4 + e] = (__bf16)hv1[e];
          }
          ax[m][ks] = fx;
          ah[m][ks] = fh;
        }
      }

      // ---- MFMA accumulation: 4 gate-part accumulators ----
      f32x4 accr[2][2], accz[2][2], acca[2][2], accb[2][2];
      #pragma unroll
      for (int m = 0; m < 2; ++m)
        #pragma unroll
        for (int n = 0; n < 2; ++n) {
          accr[m][n] = zero4; accz[m][n] = zero4;
          acca[m][n] = zero4; accb[m][n] = zero4;
        }

      #pragma unroll
      for (int m = 0; m < 2; ++m)
        #pragma unroll
        for (int n = 0; n < 2; ++n)
          #pragma unroll
          for (int ks = 0; ks < 2; ++ks) {
            accr[m][n] = __builtin_amdgcn_mfma_f32_16x16x32_bf16(ax[m][ks], bw[0][n][ks], accr[m][n], 0, 0, 0);
            accr[m][n] = __builtin_amdgcn_mfma_f32_16x16x32_bf16(ah[m][ks], bw[1][n][ks], accr[m][n], 0, 0, 0);
            accz[m][n] = __builtin_amdgcn_mfma_f32_16x16x32_bf16(ax[m][ks], bw[2][n][ks], accz[m][n], 0, 0, 0);
            accz[m][n] = __builtin_amdgcn_mfma_f32_16x16x32_bf16(ah[m][ks], bw[3][n][ks], accz[m][n], 0, 0, 0);
            acca[m][n] = __builtin_amdgcn_mfma_f32_16x16x32_bf16(ax[m][ks], bw[4][n][ks], acca[m][n], 0, 0, 0);
            accb[m][n] = __builtin_amdgcn_mfma_f32_16x16x32_bf16(ah[m][ks], bw[5][n][ks], accb[m][n], 0, 0, 0);
          }

      // ---- epilogue: gates + blend, direct store ----
      // D layout (HW-verified m89): col = lane&15, row = (lane>>4)*4 + j
      #pragma unroll
      for (int m = 0; m < 2; ++m)
        #pragma unroll
        for (int n = 0; n < 2; ++n) {
          const int o = wn * 32 + n * 16 + lr;
          #pragma unroll
          for (int j = 0; j < 4; ++j) {
            const int row = brow0 + m * 16 + lg * 4 + j;
            const size_t idx = ((size_t)row * UNITS + u) * HID + o;
            const float rv = fast_sigmoid(accr[m][n][j] + brs[n]);
            const float zv = fast_sigmoid(accz[m][n][j] + bzs[n]);
            const float nv = fast_tanh(acca[m][n][j] + bins[n] +
                                       rv * (accb[m][n][j] + bhns[n]));
            const float hv = h[idx];
            out[idx] = (1.0f - zv) * nv + zv * hv;
          }
        }
    }
}

extern "C" void kernel_launch(void* const* d_in, const int* in_sizes, int n_in,
                              void* d_out, int out_size, void* d_ws, size_t ws_size,
                              hipStream_t stream) {
    const float* x    = (const float*)d_in[0];
    const float* h    = (const float*)d_in[1];
    const float* W_ir = (const float*)d_in[2];
    const float* b_ir = (const float*)d_in[3];
    const float* W_hr = (const float*)d_in[4];
    const float* b_hr = (const float*)d_in[5];
    const float* W_iz = (const float*)d_in[6];
    const float* b_iz = (const float*)d_in[7];
    const float* W_hz = (const float*)d_in[8];
    const float* b_hz = (const float*)d_in[9];
    const float* W_in = (const float*)d_in[10];
    const float* b_in = (const float*)d_in[11];
    const float* W_hn = (const float*)d_in[12];
    const float* b_hn = (const float*)d_in[13];
    float* out = (float*)d_out;

    gru_kernel<<<dim3(UNITS), dim3(256), 0, stream>>>(
        x, h, W_ir, b_ir, W_hr, b_hr, W_iz, b_iz, W_hz, b_hz,
        W_in, b_in, W_hn, b_hn, out);
}